// Round 14
// baseline (101.624 us; speedup 1.0000x reference)
//
#include <hip/hip_runtime.h>
#include <math.h>

// DIN fused pipeline, round 14: r13's VALU diet MINUS the cvt_pk inline asm
// (reverted to proven manual-RNE pack; guide m240: hand-written cvt_pk asm is
// both slower and hazard-prone on MFMA results).
//  prep: [blocks 0..2047] convert embT/embR/Wk f32->bf16 ; [2048..2303] q/u/targ bf16
//  B: grid 2048, one block per batch, 4 quarters serial, double-buffered
//     global_load_lds gather (swizzle folded into global source chunk):
//       K: k-GEMM MFMA -> kv packed via manual RNE f2bf (r12-proven)
//       T: kT overlay stores with INCREMENTAL (j,e) walk (one div per quarter)
//       S: score partials q-slice x kT -> register accumulators
//     gather indices preloaded to registers (row&7 == (tid>>4)&7 is thread-const)
//     inline finalize -> out[b].

#define HH 200
#define EE 128
#define KT_PITCH 40   // u16/row = 80 B

typedef float fp32x4 __attribute__((ext_vector_type(4)));
typedef short bf16x8 __attribute__((ext_vector_type(8)));

static __device__ __forceinline__ unsigned f2bf(float x) {
    unsigned u = __builtin_bit_cast(unsigned, x);
    return (u + 0x7FFFu + ((u >> 16) & 1u)) >> 16;   // RNE
}

// ---------------- Kernel prep: table conversion + q/u/targ projection ----------------
#define N4_T 1600000
#define N4_R 16000
#define N4_K 4096
#define N4_ALL (N4_T + N4_R + N4_K)
#define CONV_BLOCKS 2048
#define CONV_THREADS (CONV_BLOCKS * 256)

__global__ __launch_bounds__(256) void prep(
    const int* __restrict__ target, const int* __restrict__ tregion,
    const float* __restrict__ embT, const float* __restrict__ embR,
    const float* __restrict__ Wq, const float* __restrict__ Wk,
    const float* __restrict__ Wv,
    unsigned short* __restrict__ dT, unsigned short* __restrict__ dR,
    unsigned short* __restrict__ dK,
    unsigned short* __restrict__ qbf, unsigned short* __restrict__ ubf,
    unsigned short* __restrict__ tbf)
{
    const int tid = threadIdx.x;
    if (blockIdx.x < CONV_BLOCKS) {
        int idx = blockIdx.x * 256 + tid;
        for (int i = idx; i < N4_ALL; i += CONV_THREADS) {
            const float* src; unsigned short* dst;
            if (i < N4_T)             { src = embT + 4*(size_t)i;            dst = dT + 4*(size_t)i; }
            else if (i < N4_T + N4_R) { int j = i - N4_T;        src = embR + 4*(size_t)j; dst = dR + 4*(size_t)j; }
            else                      { int j = i - N4_T - N4_R; src = Wk   + 4*(size_t)j; dst = dK + 4*(size_t)j; }
            float4 v = *(const float4*)src;
            ushort4 o;
            o.x = (unsigned short)f2bf(v.x); o.y = (unsigned short)f2bf(v.y);
            o.z = (unsigned short)f2bf(v.z); o.w = (unsigned short)f2bf(v.w);
            *(ushort4*)dst = o;
        }
        return;
    }

    __shared__ float st[8][128];
    const int b0 = (blockIdx.x - CONV_BLOCKS) * 8;

    if (tid < 128) {
        int bb = tid >> 4, j = tid & 15;
        int b = b0 + bb;
        int ti = target[b], ri = tregion[b];
        *(float4*)&st[bb][j*4]      = *(const float4*)(embT + (size_t)ti*64 + j*4);
        *(float4*)&st[bb][64+j*4]   = *(const float4*)(embR + (size_t)ri*64 + j*4);
    }
    __syncthreads();

    if (tid < 128) {
        float acc[8] = {0,0,0,0,0,0,0,0};
        const float4* wr = (const float4*)(Wq + (size_t)tid*128);
        for (int e4 = 0; e4 < 32; e4++) {
            float4 w4 = wr[e4];
            #pragma unroll
            for (int bb = 0; bb < 8; bb++) {
                float4 t4 = *(const float4*)&st[bb][e4*4];
                acc[bb] += w4.x*t4.x + w4.y*t4.y + w4.z*t4.z + w4.w*t4.w;
            }
        }
        #pragma unroll
        for (int bb = 0; bb < 8; bb++) qbf[(size_t)(b0+bb)*128 + tid] = (unsigned short)f2bf(acc[bb]);
    } else {
        int e = tid - 128;
        float acc[8] = {0,0,0,0,0,0,0,0};
        for (int f = 0; f < 128; f++) {
            float wv = Wv[(size_t)f*128 + e];
            #pragma unroll
            for (int bb = 0; bb < 8; bb++) acc[bb] += st[bb][f] * wv;
        }
        #pragma unroll
        for (int bb = 0; bb < 8; bb++) ubf[(size_t)(b0+bb)*128 + e] = (unsigned short)f2bf(acc[bb]);
    }
    __syncthreads();
    {
        int bb = tid >> 5, x = (tid & 31) * 4;
        float4 t4 = *(const float4*)&st[bb][x];
        ushort4 o;
        o.x = (unsigned short)f2bf(t4.x); o.y = (unsigned short)f2bf(t4.y);
        o.z = (unsigned short)f2bf(t4.z); o.w = (unsigned short)f2bf(t4.w);
        *(ushort4*)&tbf[(size_t)(b0+bb)*128 + x] = o;
    }
}

// ---------------- Kernel B: fused, VALU-lean (no inline asm) ----------------
__global__ __launch_bounds__(256, 4) void din_fused(
    const int* __restrict__ history, const int* __restrict__ hregion,
    const unsigned short* __restrict__ dT, const unsigned short* __restrict__ dR,
    const unsigned short* __restrict__ wk, const unsigned short* __restrict__ qb,
    const unsigned short* __restrict__ ub, const unsigned short* __restrict__ tb,
    const int* __restrict__ target, const float* __restrict__ hvr,
    float* __restrict__ out)
{
    __shared__ unsigned short bufA[8192];   // hist[64][128] linear / kT overlay
    __shared__ unsigned short bufB[8192];
    __shared__ float s_hd[200], s_td[200], s_sc[200];
    __shared__ float s_red[4];

    const int b = blockIdx.x;
    const int tid = threadIdx.x;
    const int lane = tid & 63, w = tid >> 6;
    const int c = lane & 15, g = lane >> 4;
    const int e0 = 8 * g;

    // ---- gather constants: row&7 == (tid>>4)&7 is thread-constant ----
    const int p  = tid >> 4;           // row within 16-row group
    const int jj = tid & 15;           // LDS chunk (linear dest)
    const int cj = jj ^ (p & 7);       // swizzled SOURCE chunk (thread-const!)
    const int* iptr = (cj < 8 ? history : hregion) + (size_t)b*200;
    const unsigned short* tabp = (cj < 8) ? dT : dR;
    const int coloff = (cj & 7) * 8;

    // preload all 16 gather indices (coalesced, 16-lane broadcast each)
    int gidx[4][4];
    #pragma unroll
    for (int qq = 0; qq < 4; qq++)
        #pragma unroll
        for (int it = 0; it < 4; it++) {
            int row = it*16 + p;
            int rr  = (row < 50) ? row : 49;
            gidx[qq][it] = iptr[qq*50 + rr];
        }

    // Wk B-fragments: wave w owns k-columns h in [32w, 32w+32)
    bf16x8 wkf[2][4];
    #pragma unroll
    for (int nt = 0; nt < 2; nt++)
        #pragma unroll
        for (int kc = 0; kc < 4; kc++)
            wkf[nt][kc] = *(const bf16x8*)(wk + (size_t)(32*w + 16*nt + c)*128 + kc*32 + e0);

    // [u|t] fragments hoisted (cols 0-7=u, 8-15=t)
    const unsigned short* utp = (c < 8 ? ub : tb) + (size_t)b*128;
    bf16x8 utf[4];
    #pragma unroll
    for (int kc = 0; kc < 4; kc++) utf[kc] = *(const bf16x8*)(utp + kc*32 + e0);

    // gather: 4 x global_load_lds(16B), LDS dest linear, swizzle in source
    auto gather_issue = [&](int qq, unsigned short* dst) {
        #pragma unroll
        for (int it = 0; it < 4; it++) {
            const unsigned short* src = tabp + (size_t)gidx[qq][it]*64 + coloff;
            __builtin_amdgcn_global_load_lds(
                (const __attribute__((address_space(1))) unsigned int*)src,
                (__attribute__((address_space(3))) unsigned int*)(dst + (size_t)(it*16 + p)*128 + jj*8),
                16, 0, 0);
        }
    };

    gather_issue(0, bufA);
    __syncthreads();

    unsigned short* cur = bufA;
    unsigned short* nxt = bufB;
    float scoreacc[4] = {0.f, 0.f, 0.f, 0.f};

    #pragma unroll 1
    for (int qq = 0; qq < 4; qq++) {
        const int rbase = qq * 50;
        if (qq < 3) gather_issue(qq + 1, nxt);

        // ---- K: 4 m-tiles; kv packed via manual RNE f2bf (r12-proven) ----
        unsigned kv[16];
        #pragma unroll
        for (int mt = 0; mt < 4; mt++) {
            const int ar = mt*16 + c;
            const unsigned swa = ((unsigned)(ar & 7)) << 4;
            bf16x8 a[4];
            #pragma unroll
            for (int kc = 0; kc < 4; kc++) {
                unsigned off = ((unsigned)(ar*256 + kc*64 + e0*2)) ^ swa;
                a[kc] = *(const bf16x8*)((const char*)cur + off);
            }
            fp32x4 acc0 = {0,0,0,0}, acc1 = {0,0,0,0};
            #pragma unroll
            for (int kc = 0; kc < 4; kc++) {
                acc0 = __builtin_amdgcn_mfma_f32_16x16x32_bf16(a[kc], wkf[0][kc], acc0, 0, 0, 0);
                acc1 = __builtin_amdgcn_mfma_f32_16x16x32_bf16(a[kc], wkf[1][kc], acc1, 0, 0, 0);
            }
            #pragma unroll
            for (int r = 0; r < 4; r++)
                kv[mt*4 + r] = f2bf(acc0[r]) | (f2bf(acc1[r]) << 16);

            if (mt == w) {
                fp32x4 hacc = {0,0,0,0};
                #pragma unroll
                for (int kc = 0; kc < 4; kc++)
                    hacc = __builtin_amdgcn_mfma_f32_16x16x32_bf16(a[kc], utf[kc], hacc, 0, 0, 0);
                if (c == 0 || c == 8) {
                    float* dst = (c == 0) ? s_hd : s_td;
                    const int slb = w*16 + 4*g;
                    #pragma unroll
                    for (int r = 0; r < 4; r++) {
                        int sl = slb + r;
                        if (sl < 50) dst[rbase + sl] = hacc[r];
                    }
                }
            }
        }
        __syncthreads();   // hist consumed (drains next-q gather too)

        // ---- T: kT stores with incremental (j,e); one div per quarter ----
        {
            unsigned f0 = 6400u*(unsigned)qq + 512u*(unsigned)g + 32u*(unsigned)w + (unsigned)c;
            unsigned e = f0 / 200u;
            unsigned j = f0 - e*200u;
            const unsigned ebase = (unsigned)(qq << 5);
            #pragma unroll
            for (int mt = 0; mt < 4; mt++) {
                #pragma unroll
                for (int r = 0; r < 4; r++) {
                    int sl = mt*16 + 4*g + r;
                    if (sl < 50) {
                        unsigned v = kv[mt*4 + r];
                        unsigned j2 = j + 16u, e2 = e;
                        if (j2 >= 200u) { j2 -= 200u; e2++; }
                        cur[j*KT_PITCH + (e - ebase)]   = (unsigned short)v;
                        cur[j2*KT_PITCH + (e2 - ebase)] = (unsigned short)(v >> 16);
                    }
                    if (r < 3) { j += 128u; if (j >= 200u) { j -= 200u; e++; } }
                    else       { j += 64u; e += 8u; if (j >= 200u) { j -= 200u; e++; } }
                }
            }
        }
        __syncthreads();

        // ---- S: score partials (one K=32 MFMA per j-tile) ----
        const bf16x8 af = *(const bf16x8*)(qb + (size_t)b*128 + (qq<<5) + e0);
        int slot = 0;
        for (int jt = w; jt < 13; jt += 4, slot++) {
            int jr = jt*16 + c; if (jr > 199) jr = 199;
            bf16x8 bfr = *(const bf16x8*)&cur[(unsigned)jr*KT_PITCH + e0];
            fp32x4 sacc = {0,0,0,0};
            sacc = __builtin_amdgcn_mfma_f32_16x16x32_bf16(af, bfr, sacc, 0, 0, 0);
            scoreacc[slot] += sacc[0];
        }
        __syncthreads();

        unsigned short* t = cur; cur = nxt; nxt = t;
    }

    // ---- inline finalize ----
    {
        int slot = 0;
        for (int jt = w; jt < 13; jt += 4, slot++) {
            if (lane < 16) {
                int j = jt*16 + lane;
                if (j < 200) s_sc[j] = scoreacc[slot];
            }
        }
    }
    __syncthreads();

    const int tgt = target[b];
    float ev = 0.f;
    if (tid < 200) {
        int uh = history[(size_t)b*200 + tid];
        ev = (uh != tgt) ? expf(s_sc[tid] * 0.088388347648318447f) : 0.f;
    }
    float sum = ev;
    #pragma unroll
    for (int m = 1; m < 64; m <<= 1) sum += __shfl_xor(sum, m, 64);
    if (lane == 0) s_red[w] = sum;
    __syncthreads();
    float total = (s_red[0] + s_red[1]) + (s_red[2] + s_red[3]);

    float pv = 0.f;
    if (tid < 200) {
        float attn = ev * rsqrtf(total);          // exp_A / sum^0.5
        pv = attn * s_hd[tid] + hvr[tid] * s_td[tid];
    }
    float ps = pv;
    #pragma unroll
    for (int m = 1; m < 64; m <<= 1) ps += __shfl_xor(ps, m, 64);
    if (lane == 0) s_red[w] = ps;
    __syncthreads();
    if (tid == 0) {
        float pred = (s_red[0] + s_red[1]) + (s_red[2] + s_red[3]);
        out[b] = 1.0f / (1.0f + expf(-pred));
    }
}

extern "C" void kernel_launch(void* const* d_in, const int* in_sizes, int n_in,
                              void* d_out, int out_size, void* d_ws, size_t ws_size,
                              hipStream_t stream) {
    const int*   history = (const int*)d_in[0];
    const int*   target  = (const int*)d_in[1];
    const int*   hregion = (const int*)d_in[2];
    const int*   tregion = (const int*)d_in[3];
    const float* hvrate  = (const float*)d_in[4];
    const float* embT    = (const float*)d_in[5];
    const float* embR    = (const float*)d_in[6];
    const float* Wq      = (const float*)d_in[7];
    const float* Wk      = (const float*)d_in[8];
    const float* Wv      = (const float*)d_in[9];
    float* outp = (float*)d_out;

    char* ws = (char*)d_ws;
    unsigned short* dT = (unsigned short*)(ws);                 // 12,800,000 B
    unsigned short* dR = (unsigned short*)(ws + 12800000);      //    128,000
    unsigned short* dK = (unsigned short*)(ws + 12928000);      //     32,768
    unsigned short* ub = (unsigned short*)(ws + 12960768);      //    524,288
    unsigned short* tb = (unsigned short*)(ws + 13485056);      //    524,288
    unsigned short* qb = (unsigned short*)(ws + 14009344);      //    524,288  (end 14,533,632)

    hipLaunchKernelGGL(prep, dim3(CONV_BLOCKS + 256), dim3(256), 0, stream,
                       target, tregion, embT, embR, Wq, Wk, Wv,
                       dT, dR, dK, qb, ub, tb);
    hipLaunchKernelGGL(din_fused, dim3(2048), dim3(256), 0, stream,
                       history, hregion, dT, dR, dK, qb, ub, tb,
                       target, hvrate, outp);
}

// Round 15
// 80.260 us; speedup vs baseline: 1.2662x; 1.2662x over previous
//
#include <hip/hip_runtime.h>
#include <math.h>

// DIN fused pipeline, round 15: r12 structure + verified r13 improvements,
// indices back in LDS (r14's register gidx was runtime-indexed -> scratch, rule #20).
//  prep: [blocks 0..2047] convert embT/embR/Wk f32->bf16 ; [2048..2303] q/u/targ bf16
//  B: grid 2048, one block per batch, 4 quarters serial, double-buffered
//     global_load_lds gather (swizzle folded into global source chunk):
//       K: k-GEMM MFMA -> kv packed via manual RNE f2bf; fused hdot/tdot (mt==w,
//          utf hoisted)
//       T: kT overlay stores with INCREMENTAL (j,e) walk (one div per quarter)
//       S: score partials q-slice x kT -> register accumulators
//     inline finalize -> out[b].

#define HH 200
#define EE 128
#define KT_PITCH 40   // u16/row = 80 B

typedef float fp32x4 __attribute__((ext_vector_type(4)));
typedef short bf16x8 __attribute__((ext_vector_type(8)));

static __device__ __forceinline__ unsigned f2bf(float x) {
    unsigned u = __builtin_bit_cast(unsigned, x);
    return (u + 0x7FFFu + ((u >> 16) & 1u)) >> 16;   // RNE
}

// ---------------- Kernel prep: table conversion + q/u/targ projection ----------------
#define N4_T 1600000
#define N4_R 16000
#define N4_K 4096
#define N4_ALL (N4_T + N4_R + N4_K)
#define CONV_BLOCKS 2048
#define CONV_THREADS (CONV_BLOCKS * 256)

__global__ __launch_bounds__(256) void prep(
    const int* __restrict__ target, const int* __restrict__ tregion,
    const float* __restrict__ embT, const float* __restrict__ embR,
    const float* __restrict__ Wq, const float* __restrict__ Wk,
    const float* __restrict__ Wv,
    unsigned short* __restrict__ dT, unsigned short* __restrict__ dR,
    unsigned short* __restrict__ dK,
    unsigned short* __restrict__ qbf, unsigned short* __restrict__ ubf,
    unsigned short* __restrict__ tbf)
{
    const int tid = threadIdx.x;
    if (blockIdx.x < CONV_BLOCKS) {
        int idx = blockIdx.x * 256 + tid;
        for (int i = idx; i < N4_ALL; i += CONV_THREADS) {
            const float* src; unsigned short* dst;
            if (i < N4_T)             { src = embT + 4*(size_t)i;            dst = dT + 4*(size_t)i; }
            else if (i < N4_T + N4_R) { int j = i - N4_T;        src = embR + 4*(size_t)j; dst = dR + 4*(size_t)j; }
            else                      { int j = i - N4_T - N4_R; src = Wk   + 4*(size_t)j; dst = dK + 4*(size_t)j; }
            float4 v = *(const float4*)src;
            ushort4 o;
            o.x = (unsigned short)f2bf(v.x); o.y = (unsigned short)f2bf(v.y);
            o.z = (unsigned short)f2bf(v.z); o.w = (unsigned short)f2bf(v.w);
            *(ushort4*)dst = o;
        }
        return;
    }

    __shared__ float st[8][128];
    const int b0 = (blockIdx.x - CONV_BLOCKS) * 8;

    if (tid < 128) {
        int bb = tid >> 4, j = tid & 15;
        int b = b0 + bb;
        int ti = target[b], ri = tregion[b];
        *(float4*)&st[bb][j*4]      = *(const float4*)(embT + (size_t)ti*64 + j*4);
        *(float4*)&st[bb][64+j*4]   = *(const float4*)(embR + (size_t)ri*64 + j*4);
    }
    __syncthreads();

    if (tid < 128) {
        float acc[8] = {0,0,0,0,0,0,0,0};
        const float4* wr = (const float4*)(Wq + (size_t)tid*128);
        for (int e4 = 0; e4 < 32; e4++) {
            float4 w4 = wr[e4];
            #pragma unroll
            for (int bb = 0; bb < 8; bb++) {
                float4 t4 = *(const float4*)&st[bb][e4*4];
                acc[bb] += w4.x*t4.x + w4.y*t4.y + w4.z*t4.z + w4.w*t4.w;
            }
        }
        #pragma unroll
        for (int bb = 0; bb < 8; bb++) qbf[(size_t)(b0+bb)*128 + tid] = (unsigned short)f2bf(acc[bb]);
    } else {
        int e = tid - 128;
        float acc[8] = {0,0,0,0,0,0,0,0};
        for (int f = 0; f < 128; f++) {
            float wv = Wv[(size_t)f*128 + e];
            #pragma unroll
            for (int bb = 0; bb < 8; bb++) acc[bb] += st[bb][f] * wv;
        }
        #pragma unroll
        for (int bb = 0; bb < 8; bb++) ubf[(size_t)(b0+bb)*128 + e] = (unsigned short)f2bf(acc[bb]);
    }
    __syncthreads();
    {
        int bb = tid >> 5, x = (tid & 31) * 4;
        float4 t4 = *(const float4*)&st[bb][x];
        ushort4 o;
        o.x = (unsigned short)f2bf(t4.x); o.y = (unsigned short)f2bf(t4.y);
        o.z = (unsigned short)f2bf(t4.z); o.w = (unsigned short)f2bf(t4.w);
        *(ushort4*)&tbf[(size_t)(b0+bb)*128 + x] = o;
    }
}

// ---------------- Kernel B: fused; LDS-staged indices (no scratch) ----------------
__global__ __launch_bounds__(256, 4) void din_fused(
    const int* __restrict__ history, const int* __restrict__ hregion,
    const unsigned short* __restrict__ dT, const unsigned short* __restrict__ dR,
    const unsigned short* __restrict__ wk, const unsigned short* __restrict__ qb,
    const unsigned short* __restrict__ ub, const unsigned short* __restrict__ tb,
    const int* __restrict__ target, const float* __restrict__ hvr,
    float* __restrict__ out)
{
    __shared__ unsigned short bufA[8192];   // hist[64][128] linear / kT overlay
    __shared__ unsigned short bufB[8192];
    __shared__ int   s_ih[200], s_ir[200];
    __shared__ float s_hd[200], s_td[200], s_sc[200];
    __shared__ float s_red[4];

    const int b = blockIdx.x;
    const int tid = threadIdx.x;
    const int lane = tid & 63, w = tid >> 6;
    const int c = lane & 15, g = lane >> 4;
    const int e0 = 8 * g;

    // index preload to LDS (runtime-indexable; rule #20 safe)
    if (tid < 200) {
        s_ih[tid] = history[(size_t)b*200 + tid];
        s_ir[tid] = hregion[(size_t)b*200 + tid];
    }

    // ---- gather constants: row&7 == (tid>>4)&7 is thread-constant ----
    const int p  = tid >> 4;           // row within 16-row group
    const int jj = tid & 15;           // LDS chunk (linear dest)
    const int cj = jj ^ (p & 7);       // swizzled SOURCE chunk (thread-const)
    const bool useT = (cj < 8);
    const unsigned short* tabp = useT ? dT : dR;
    const int coloff = (cj & 7) * 8;

    // Wk B-fragments: wave w owns k-columns h in [32w, 32w+32)
    bf16x8 wkf[2][4];
    #pragma unroll
    for (int nt = 0; nt < 2; nt++)
        #pragma unroll
        for (int kc = 0; kc < 4; kc++)
            wkf[nt][kc] = *(const bf16x8*)(wk + (size_t)(32*w + 16*nt + c)*128 + kc*32 + e0);

    // [u|t] fragments hoisted (cols 0-7=u, 8-15=t)
    const unsigned short* utp = (c < 8 ? ub : tb) + (size_t)b*128;
    bf16x8 utf[4];
    #pragma unroll
    for (int kc = 0; kc < 4; kc++) utf[kc] = *(const bf16x8*)(utp + kc*32 + e0);

    __syncthreads();   // s_ih/s_ir visible

    // gather: 4 x global_load_lds(16B), LDS dest linear, swizzle in source;
    // index from LDS (useT selects table; both arrays adjacent)
    auto gather_issue = [&](int qq, unsigned short* dst) {
        const int rb = qq * 50;
        #pragma unroll
        for (int it = 0; it < 4; it++) {
            int row = it*16 + p;
            int rr  = (row < 50) ? row : 49;
            int idx = useT ? s_ih[rb + rr] : s_ir[rb + rr];
            const unsigned short* src = tabp + (size_t)idx*64 + coloff;
            __builtin_amdgcn_global_load_lds(
                (const __attribute__((address_space(1))) unsigned int*)src,
                (__attribute__((address_space(3))) unsigned int*)(dst + (size_t)(it*16 + p)*128 + jj*8),
                16, 0, 0);
        }
    };

    gather_issue(0, bufA);
    __syncthreads();

    unsigned short* cur = bufA;
    unsigned short* nxt = bufB;
    float scoreacc[4] = {0.f, 0.f, 0.f, 0.f};

    #pragma unroll 1
    for (int qq = 0; qq < 4; qq++) {
        const int rbase = qq * 50;
        if (qq < 3) gather_issue(qq + 1, nxt);

        // ---- K: 4 m-tiles; kv packed via manual RNE f2bf ----
        unsigned kv[16];
        #pragma unroll
        for (int mt = 0; mt < 4; mt++) {
            const int ar = mt*16 + c;
            const unsigned swa = ((unsigned)(ar & 7)) << 4;
            bf16x8 a[4];
            #pragma unroll
            for (int kc = 0; kc < 4; kc++) {
                unsigned off = ((unsigned)(ar*256 + kc*64 + e0*2)) ^ swa;
                a[kc] = *(const bf16x8*)((const char*)cur + off);
            }
            fp32x4 acc0 = {0,0,0,0}, acc1 = {0,0,0,0};
            #pragma unroll
            for (int kc = 0; kc < 4; kc++) {
                acc0 = __builtin_amdgcn_mfma_f32_16x16x32_bf16(a[kc], wkf[0][kc], acc0, 0, 0, 0);
                acc1 = __builtin_amdgcn_mfma_f32_16x16x32_bf16(a[kc], wkf[1][kc], acc1, 0, 0, 0);
            }
            #pragma unroll
            for (int r = 0; r < 4; r++)
                kv[mt*4 + r] = f2bf(acc0[r]) | (f2bf(acc1[r]) << 16);

            if (mt == w) {
                fp32x4 hacc = {0,0,0,0};
                #pragma unroll
                for (int kc = 0; kc < 4; kc++)
                    hacc = __builtin_amdgcn_mfma_f32_16x16x32_bf16(a[kc], utf[kc], hacc, 0, 0, 0);
                if (c == 0 || c == 8) {
                    float* dst = (c == 0) ? s_hd : s_td;
                    const int slb = w*16 + 4*g;
                    #pragma unroll
                    for (int r = 0; r < 4; r++) {
                        int sl = slb + r;
                        if (sl < 50) dst[rbase + sl] = hacc[r];
                    }
                }
            }
        }
        __syncthreads();   // hist consumed (drains next-q gather too)

        // ---- T: kT stores with incremental (j,e); one div per quarter ----
        {
            unsigned f0 = 6400u*(unsigned)qq + 512u*(unsigned)g + 32u*(unsigned)w + (unsigned)c;
            unsigned e = f0 / 200u;
            unsigned j = f0 - e*200u;
            const unsigned ebase = (unsigned)(qq << 5);
            #pragma unroll
            for (int mt = 0; mt < 4; mt++) {
                #pragma unroll
                for (int r = 0; r < 4; r++) {
                    int sl = mt*16 + 4*g + r;
                    if (sl < 50) {
                        unsigned v = kv[mt*4 + r];
                        unsigned j2 = j + 16u, e2 = e;
                        if (j2 >= 200u) { j2 -= 200u; e2++; }
                        cur[j*KT_PITCH + (e - ebase)]   = (unsigned short)v;
                        cur[j2*KT_PITCH + (e2 - ebase)] = (unsigned short)(v >> 16);
                    }
                    if (r < 3) { j += 128u; if (j >= 200u) { j -= 200u; e++; } }
                    else       { j += 64u; e += 8u; if (j >= 200u) { j -= 200u; e++; } }
                }
            }
        }
        __syncthreads();

        // ---- S: score partials (one K=32 MFMA per j-tile) ----
        const bf16x8 af = *(const bf16x8*)(qb + (size_t)b*128 + (qq<<5) + e0);
        int slot = 0;
        for (int jt = w; jt < 13; jt += 4, slot++) {
            int jr = jt*16 + c; if (jr > 199) jr = 199;
            bf16x8 bfr = *(const bf16x8*)&cur[(unsigned)jr*KT_PITCH + e0];
            fp32x4 sacc = {0,0,0,0};
            sacc = __builtin_amdgcn_mfma_f32_16x16x32_bf16(af, bfr, sacc, 0, 0, 0);
            scoreacc[slot] += sacc[0];
        }
        __syncthreads();

        unsigned short* t = cur; cur = nxt; nxt = t;
    }

    // ---- inline finalize ----
    {
        int slot = 0;
        for (int jt = w; jt < 13; jt += 4, slot++) {
            if (lane < 16) {
                int j = jt*16 + lane;
                if (j < 200) s_sc[j] = scoreacc[slot];
            }
        }
    }
    __syncthreads();

    const int tgt = target[b];
    float ev = 0.f;
    if (tid < 200) {
        ev = (s_ih[tid] != tgt) ? expf(s_sc[tid] * 0.088388347648318447f) : 0.f;
    }
    float sum = ev;
    #pragma unroll
    for (int m = 1; m < 64; m <<= 1) sum += __shfl_xor(sum, m, 64);
    if (lane == 0) s_red[w] = sum;
    __syncthreads();
    float total = (s_red[0] + s_red[1]) + (s_red[2] + s_red[3]);

    float pv = 0.f;
    if (tid < 200) {
        float attn = ev * rsqrtf(total);          // exp_A / sum^0.5
        pv = attn * s_hd[tid] + hvr[tid] * s_td[tid];
    }
    float ps = pv;
    #pragma unroll
    for (int m = 1; m < 64; m <<= 1) ps += __shfl_xor(ps, m, 64);
    if (lane == 0) s_red[w] = ps;
    __syncthreads();
    if (tid == 0) {
        float pred = (s_red[0] + s_red[1]) + (s_red[2] + s_red[3]);
        out[b] = 1.0f / (1.0f + expf(-pred));
    }
}

extern "C" void kernel_launch(void* const* d_in, const int* in_sizes, int n_in,
                              void* d_out, int out_size, void* d_ws, size_t ws_size,
                              hipStream_t stream) {
    const int*   history = (const int*)d_in[0];
    const int*   target  = (const int*)d_in[1];
    const int*   hregion = (const int*)d_in[2];
    const int*   tregion = (const int*)d_in[3];
    const float* hvrate  = (const float*)d_in[4];
    const float* embT    = (const float*)d_in[5];
    const float* embR    = (const float*)d_in[6];
    const float* Wq      = (const float*)d_in[7];
    const float* Wk      = (const float*)d_in[8];
    const float* Wv      = (const float*)d_in[9];
    float* outp = (float*)d_out;

    char* ws = (char*)d_ws;
    unsigned short* dT = (unsigned short*)(ws);                 // 12,800,000 B
    unsigned short* dR = (unsigned short*)(ws + 12800000);      //    128,000
    unsigned short* dK = (unsigned short*)(ws + 12928000);      //     32,768
    unsigned short* ub = (unsigned short*)(ws + 12960768);      //    524,288
    unsigned short* tb = (unsigned short*)(ws + 13485056);      //    524,288
    unsigned short* qb = (unsigned short*)(ws + 14009344);      //    524,288  (end 14,533,632)

    hipLaunchKernelGGL(prep, dim3(CONV_BLOCKS + 256), dim3(256), 0, stream,
                       target, tregion, embT, embR, Wq, Wk, Wv,
                       dT, dR, dK, qb, ub, tb);
    hipLaunchKernelGGL(din_fused, dim3(2048), dim3(256), 0, stream,
                       history, hregion, dT, dR, dK, qb, ub, tb,
                       target, hvrate, outp);
}

// Round 16
// 69.180 us; speedup vs baseline: 1.4690x; 1.1602x over previous
//
#include <hip/hip_runtime.h>
#include <math.h>

// DIN fused pipeline, round 16: EXACT r12 structure (53.7 µs proven, no spill)
// + ONE grafted change: incremental (j,e) walk in the T phase (HW-verified in
// r14/r15). The r13 utf hoist is dropped — it caused 43 MB of scratch spill.
//  prep: [blocks 0..2047] convert embT/embR/Wk f32->bf16 ; [2048..2303] q/u/targ bf16
//  B: grid 2048, one block per batch, 4 quarters serial, double-buffered
//     global_load_lds gather (swizzle folded into global source chunk):
//       K: k-GEMM MFMA -> kv packed via manual RNE f2bf; fused hdot/tdot (mt==w,
//          utf loaded per quarter as in r12)
//       T: kT overlay stores, incremental (j,e) walk (one div per quarter)
//       S: score partials q-slice x kT -> register accumulators
//     inline finalize -> out[b].

#define HH 200
#define EE 128
#define KT_PITCH 40   // u16/row = 80 B

typedef float fp32x4 __attribute__((ext_vector_type(4)));
typedef short bf16x8 __attribute__((ext_vector_type(8)));

static __device__ __forceinline__ unsigned f2bf(float x) {
    unsigned u = __builtin_bit_cast(unsigned, x);
    return (u + 0x7FFFu + ((u >> 16) & 1u)) >> 16;   // RNE
}

// ---------------- Kernel prep: table conversion + q/u/targ projection ----------------
#define N4_T 1600000
#define N4_R 16000
#define N4_K 4096
#define N4_ALL (N4_T + N4_R + N4_K)
#define CONV_BLOCKS 2048
#define CONV_THREADS (CONV_BLOCKS * 256)

__global__ __launch_bounds__(256) void prep(
    const int* __restrict__ target, const int* __restrict__ tregion,
    const float* __restrict__ embT, const float* __restrict__ embR,
    const float* __restrict__ Wq, const float* __restrict__ Wk,
    const float* __restrict__ Wv,
    unsigned short* __restrict__ dT, unsigned short* __restrict__ dR,
    unsigned short* __restrict__ dK,
    unsigned short* __restrict__ qbf, unsigned short* __restrict__ ubf,
    unsigned short* __restrict__ tbf)
{
    const int tid = threadIdx.x;
    if (blockIdx.x < CONV_BLOCKS) {
        int idx = blockIdx.x * 256 + tid;
        for (int i = idx; i < N4_ALL; i += CONV_THREADS) {
            const float* src; unsigned short* dst;
            if (i < N4_T)             { src = embT + 4*(size_t)i;            dst = dT + 4*(size_t)i; }
            else if (i < N4_T + N4_R) { int j = i - N4_T;        src = embR + 4*(size_t)j; dst = dR + 4*(size_t)j; }
            else                      { int j = i - N4_T - N4_R; src = Wk   + 4*(size_t)j; dst = dK + 4*(size_t)j; }
            float4 v = *(const float4*)src;
            ushort4 o;
            o.x = (unsigned short)f2bf(v.x); o.y = (unsigned short)f2bf(v.y);
            o.z = (unsigned short)f2bf(v.z); o.w = (unsigned short)f2bf(v.w);
            *(ushort4*)dst = o;
        }
        return;
    }

    __shared__ float st[8][128];
    const int b0 = (blockIdx.x - CONV_BLOCKS) * 8;

    if (tid < 128) {
        int bb = tid >> 4, j = tid & 15;
        int b = b0 + bb;
        int ti = target[b], ri = tregion[b];
        *(float4*)&st[bb][j*4]      = *(const float4*)(embT + (size_t)ti*64 + j*4);
        *(float4*)&st[bb][64+j*4]   = *(const float4*)(embR + (size_t)ri*64 + j*4);
    }
    __syncthreads();

    if (tid < 128) {
        float acc[8] = {0,0,0,0,0,0,0,0};
        const float4* wr = (const float4*)(Wq + (size_t)tid*128);
        for (int e4 = 0; e4 < 32; e4++) {
            float4 w4 = wr[e4];
            #pragma unroll
            for (int bb = 0; bb < 8; bb++) {
                float4 t4 = *(const float4*)&st[bb][e4*4];
                acc[bb] += w4.x*t4.x + w4.y*t4.y + w4.z*t4.z + w4.w*t4.w;
            }
        }
        #pragma unroll
        for (int bb = 0; bb < 8; bb++) qbf[(size_t)(b0+bb)*128 + tid] = (unsigned short)f2bf(acc[bb]);
    } else {
        int e = tid - 128;
        float acc[8] = {0,0,0,0,0,0,0,0};
        for (int f = 0; f < 128; f++) {
            float wv = Wv[(size_t)f*128 + e];
            #pragma unroll
            for (int bb = 0; bb < 8; bb++) acc[bb] += st[bb][f] * wv;
        }
        #pragma unroll
        for (int bb = 0; bb < 8; bb++) ubf[(size_t)(b0+bb)*128 + e] = (unsigned short)f2bf(acc[bb]);
    }
    __syncthreads();
    {
        int bb = tid >> 5, x = (tid & 31) * 4;
        float4 t4 = *(const float4*)&st[bb][x];
        ushort4 o;
        o.x = (unsigned short)f2bf(t4.x); o.y = (unsigned short)f2bf(t4.y);
        o.z = (unsigned short)f2bf(t4.z); o.w = (unsigned short)f2bf(t4.w);
        *(ushort4*)&tbf[(size_t)(b0+bb)*128 + x] = o;
    }
}

// ---------------- Kernel B: fused, double-buffered global_load_lds gather ----------------
__global__ __launch_bounds__(256, 4) void din_fused(
    const int* __restrict__ history, const int* __restrict__ hregion,
    const unsigned short* __restrict__ dT, const unsigned short* __restrict__ dR,
    const unsigned short* __restrict__ wk, const unsigned short* __restrict__ qb,
    const unsigned short* __restrict__ ub, const unsigned short* __restrict__ tb,
    const int* __restrict__ target, const float* __restrict__ hvr,
    float* __restrict__ out)
{
    __shared__ unsigned short bufA[8192];   // hist[64][128] linear / kT overlay
    __shared__ unsigned short bufB[8192];
    __shared__ int   s_ih[200], s_ir[200];
    __shared__ float s_hd[200], s_td[200], s_sc[200];
    __shared__ float s_red[4];

    const int b = blockIdx.x;
    const int tid = threadIdx.x;
    const int lane = tid & 63, w = tid >> 6;
    const int c = lane & 15, g = lane >> 4;
    const int e0 = 8 * g;

    // index preload (kills idx->row chained latency in the gather)
    if (tid < 200) {
        s_ih[tid] = history[(size_t)b*200 + tid];
        s_ir[tid] = hregion[(size_t)b*200 + tid];
    }

    // Wk B-fragments: wave w owns k-columns h in [32w, 32w+32)
    bf16x8 wkf[2][4];
    #pragma unroll
    for (int nt = 0; nt < 2; nt++)
        #pragma unroll
        for (int kc = 0; kc < 4; kc++)
            wkf[nt][kc] = *(const bf16x8*)(wk + (size_t)(32*w + 16*nt + c)*128 + kc*32 + e0);

    const unsigned short* utp = (c < 8 ? ub : tb) + (size_t)b*128;
    __syncthreads();   // s_ih/s_ir visible

    // gather issue: 4 x global_load_lds(16B); LDS dest linear in lane;
    // bank swizzle folded into the global source chunk index.
    auto gather_issue = [&](int qq, unsigned short* dst) {
        const int rb = qq * 50;
        #pragma unroll
        for (int it = 0; it < 4; it++) {
            int row = it*16 + (tid >> 4);
            int rr  = (row < 50) ? row : 49;     // rows 50..63 duplicate 49 (pad)
            int cj  = (tid & 15) ^ (row & 7);    // pre-swizzled source chunk
            const unsigned short* src = (cj < 8)
                ? dT + (size_t)s_ih[rb + rr]*64 + cj*8
                : dR + (size_t)s_ir[rb + rr]*64 + (cj-8)*8;
            __builtin_amdgcn_global_load_lds(
                (const __attribute__((address_space(1))) unsigned int*)src,
                (__attribute__((address_space(3))) unsigned int*)(dst + (size_t)row*128 + (tid & 15)*8),
                16, 0, 0);
        }
    };

    gather_issue(0, bufA);
    __syncthreads();   // hist(0) ready

    unsigned short* cur = bufA;
    unsigned short* nxt = bufB;
    float scoreacc[4] = {0.f, 0.f, 0.f, 0.f};

    #pragma unroll 1
    for (int qq = 0; qq < 4; qq++) {
        const int rbase = qq * 50;
        if (qq < 3) gather_issue(qq + 1, nxt);   // async; drains at K-end barrier

        // ---- K: 4 m-tiles; kv packed via manual RNE f2bf; hdot/tdot (mt==w) ----
        unsigned kv[16];
        #pragma unroll
        for (int mt = 0; mt < 4; mt++) {
            const int ar = mt*16 + c;
            const unsigned swa = ((unsigned)(ar & 7)) << 4;
            bf16x8 a[4];
            #pragma unroll
            for (int kc = 0; kc < 4; kc++) {
                unsigned off = ((unsigned)(ar*256 + kc*64 + e0*2)) ^ swa;
                a[kc] = *(const bf16x8*)((const char*)cur + off);
            }
            fp32x4 acc0 = {0,0,0,0}, acc1 = {0,0,0,0};
            #pragma unroll
            for (int kc = 0; kc < 4; kc++) {
                acc0 = __builtin_amdgcn_mfma_f32_16x16x32_bf16(a[kc], wkf[0][kc], acc0, 0, 0, 0);
                acc1 = __builtin_amdgcn_mfma_f32_16x16x32_bf16(a[kc], wkf[1][kc], acc1, 0, 0, 0);
            }
            #pragma unroll
            for (int r = 0; r < 4; r++)
                kv[mt*4 + r] = f2bf(acc0[r]) | (f2bf(acc1[r]) << 16);

            if (mt == w) {
                fp32x4 hacc = {0,0,0,0};
                #pragma unroll
                for (int kc = 0; kc < 4; kc++) {
                    bf16x8 utf = *(const bf16x8*)(utp + kc*32 + e0);   // per-quarter load (r12)
                    hacc = __builtin_amdgcn_mfma_f32_16x16x32_bf16(a[kc], utf, hacc, 0, 0, 0);
                }
                if (c == 0 || c == 8) {
                    float* dst = (c == 0) ? s_hd : s_td;
                    const int slb = w*16 + 4*g;
                    #pragma unroll
                    for (int r = 0; r < 4; r++) {
                        int sl = slb + r;
                        if (sl < 50) dst[rbase + sl] = hacc[r];
                    }
                }
            }
        }
        __syncthreads();   // hist consumed (drains next-q gather too)

        // ---- T: kT stores with incremental (j,e); one div per quarter ----
        {
            unsigned f0 = 6400u*(unsigned)qq + 512u*(unsigned)g + 32u*(unsigned)w + (unsigned)c;
            unsigned e = f0 / 200u;
            unsigned j = f0 - e*200u;
            const unsigned ebase = (unsigned)(qq << 5);
            #pragma unroll
            for (int mt = 0; mt < 4; mt++) {
                #pragma unroll
                for (int r = 0; r < 4; r++) {
                    int sl = mt*16 + 4*g + r;
                    if (sl < 50) {
                        unsigned v = kv[mt*4 + r];
                        unsigned j2 = j + 16u, e2 = e;
                        if (j2 >= 200u) { j2 -= 200u; e2++; }
                        cur[j*KT_PITCH + (e - ebase)]   = (unsigned short)v;
                        cur[j2*KT_PITCH + (e2 - ebase)] = (unsigned short)(v >> 16);
                    }
                    if (r < 3) { j += 128u; if (j >= 200u) { j -= 200u; e++; } }
                    else       { j += 64u; e += 8u; if (j >= 200u) { j -= 200u; e++; } }
                }
            }
        }
        __syncthreads();

        // ---- S: score partials (one K=32 MFMA per j-tile) ----
        const bf16x8 af = *(const bf16x8*)(qb + (size_t)b*128 + (qq<<5) + e0);
        int slot = 0;
        for (int jt = w; jt < 13; jt += 4, slot++) {
            int jr = jt*16 + c; if (jr > 199) jr = 199;
            bf16x8 bfr = *(const bf16x8*)&cur[(unsigned)jr*KT_PITCH + e0];
            fp32x4 sacc = {0,0,0,0};
            sacc = __builtin_amdgcn_mfma_f32_16x16x32_bf16(af, bfr, sacc, 0, 0, 0);
            scoreacc[slot] += sacc[0];
        }
        __syncthreads();   // kT consumed; cur free for next gather

        unsigned short* t = cur; cur = nxt; nxt = t;
    }

    // ---- inline finalize ----
    {
        int slot = 0;
        for (int jt = w; jt < 13; jt += 4, slot++) {
            if (lane < 16) {
                int j = jt*16 + lane;
                if (j < 200) s_sc[j] = scoreacc[slot];
            }
        }
    }
    __syncthreads();

    const int tgt = target[b];
    float ev = 0.f;
    if (tid < 200) {
        ev = (s_ih[tid] != tgt) ? expf(s_sc[tid] * 0.088388347648318447f) : 0.f;
    }
    float sum = ev;
    #pragma unroll
    for (int m = 1; m < 64; m <<= 1) sum += __shfl_xor(sum, m, 64);
    if (lane == 0) s_red[w] = sum;
    __syncthreads();
    float total = (s_red[0] + s_red[1]) + (s_red[2] + s_red[3]);

    float pv = 0.f;
    if (tid < 200) {
        float attn = ev * rsqrtf(total);          // exp_A / sum^0.5
        pv = attn * s_hd[tid] + hvr[tid] * s_td[tid];
    }
    float ps = pv;
    #pragma unroll
    for (int m = 1; m < 64; m <<= 1) ps += __shfl_xor(ps, m, 64);
    if (lane == 0) s_red[w] = ps;
    __syncthreads();
    if (tid == 0) {
        float pred = (s_red[0] + s_red[1]) + (s_red[2] + s_red[3]);
        out[b] = 1.0f / (1.0f + expf(-pred));
    }
}

extern "C" void kernel_launch(void* const* d_in, const int* in_sizes, int n_in,
                              void* d_out, int out_size, void* d_ws, size_t ws_size,
                              hipStream_t stream) {
    const int*   history = (const int*)d_in[0];
    const int*   target  = (const int*)d_in[1];
    const int*   hregion = (const int*)d_in[2];
    const int*   tregion = (const int*)d_in[3];
    const float* hvrate  = (const float*)d_in[4];
    const float* embT    = (const float*)d_in[5];
    const float* embR    = (const float*)d_in[6];
    const float* Wq      = (const float*)d_in[7];
    const float* Wk      = (const float*)d_in[8];
    const float* Wv      = (const float*)d_in[9];
    float* outp = (float*)d_out;

    char* ws = (char*)d_ws;
    unsigned short* dT = (unsigned short*)(ws);                 // 12,800,000 B
    unsigned short* dR = (unsigned short*)(ws + 12800000);      //    128,000
    unsigned short* dK = (unsigned short*)(ws + 12928000);      //     32,768
    unsigned short* ub = (unsigned short*)(ws + 12960768);      //    524,288
    unsigned short* tb = (unsigned short*)(ws + 13485056);      //    524,288
    unsigned short* qb = (unsigned short*)(ws + 14009344);      //    524,288  (end 14,533,632)

    hipLaunchKernelGGL(prep, dim3(CONV_BLOCKS + 256), dim3(256), 0, stream,
                       target, tregion, embT, embR, Wq, Wk, Wv,
                       dT, dR, dK, qb, ub, tb);
    hipLaunchKernelGGL(din_fused, dim3(2048), dim3(256), 0, stream,
                       history, hregion, dT, dR, dK, qb, ub, tb,
                       target, hvrate, outp);
}